// Round 8
// baseline (32.789 us; speedup 1.0000x reference)
//
#include <hip/hip_runtime.h>
#include <math.h>

#define DD 512
#define CAT_VOCAB 512
#define TIME_START 512
#define TIME_STEPS 1000
#define NOTE_START 1512
#define NOTE_RANGE 128
#define VEL_START 1640
#define VEL_BINS 32
#define DUR_START 1672
#define DUR_STEPS 1000
#define VOCAB 2672

typedef float f32x4 __attribute__((ext_vector_type(4)));

__device__ __forceinline__ float gelu_exact(float x) {
    return 0.5f * x * (1.0f + erff(x * 0.70710678118654752440f));
}

// hardware trig: reduce to revolutions in [0,1), then v_sin/v_cos.
// |x| <= ~740 rad here -> reduction error <= ~6e-5, far under 8.25e-2 threshold.
// (absmax has been 0.0078125 since R1-with-libm -> baseline jax-vs-hip diff.)
__device__ __forceinline__ float fsin(float x) {
    float r = x * 0.15915494309189535f;   // x / (2*pi)
    r = r - floorf(r);
    return __builtin_amdgcn_sinf(r);
}
__device__ __forceinline__ float fcos(float x) {
    float r = x * 0.15915494309189535f;
    r = r - floorf(r);
    return __builtin_amdgcn_cosf(r);
}

// ---------------------------------------------------------------------------
// Kernel A: velocity e-matvec, 512 blocks = (bin b, sixteenth sx of 32 rows).
// 8 rows per wave, single flight group (max ILP, no serial loop).
// Writes raw e[32][512] and per-sixteenth partial stats (sum, sumsq).
// ---------------------------------------------------------------------------
__global__ __launch_bounds__(256) void vel_e_kernel(
    const float* __restrict__ vel_w1, const float* __restrict__ vel_b1,
    const float* __restrict__ vel_w2, const float* __restrict__ vel_b2,
    float* __restrict__ e_tab,        // [32][512]
    float* __restrict__ stats)        // [32][16][2]
{
    __shared__ float e_lds[32];

    const int blk = blockIdx.x;           // 0..511
    const int b   = blk >> 4;             // bin 0..31
    const int sx  = blk & 15;             // sixteenth 0..15
    const float vn = (float)b / 32.0f;
    const int tid = threadIdx.x;
    const int lane = tid & 63;
    const int wave = tid >> 6;

    // lane-local h[4*lane .. 4*lane+3] in registers (coalesced w1/b1 loads)
    const float4 w1v = *(const float4*)(vel_w1 + lane * 4);
    const float4 b1v = *(const float4*)(vel_b1 + lane * 4);
    float4 hv;
    hv.x = gelu_exact(vn * w1v.x + b1v.x);
    hv.y = gelu_exact(vn * w1v.y + b1v.y);
    hv.z = gelu_exact(vn * w1v.z + b1v.z);
    hv.w = gelu_exact(vn * w1v.w + b1v.w);

    // wave handles 8 rows, all in flight (independent butterfly trees)
    const int rbase = sx * 32 + wave * 8;  // row within bin
    float p[8];
    #pragma unroll
    for (int k = 0; k < 8; ++k) {
        const float4 w2v = *(const float4*)(vel_w2 + (size_t)(rbase + k) * 256 + lane * 4);
        p[k] = w2v.x * hv.x + w2v.y * hv.y + w2v.z * hv.z + w2v.w * hv.w;
    }
    #pragma unroll
    for (int off = 32; off > 0; off >>= 1) {
        #pragma unroll
        for (int k = 0; k < 8; ++k) p[k] += __shfl_xor(p[k], off);
    }
    #pragma unroll
    for (int k = 0; k < 8; ++k) {
        if (lane == k) e_lds[wave * 8 + k] = p[k] + vel_b2[rbase + k];
    }
    __syncthreads();

    // threads 0..31: write e + per-sixteenth partial stats
    if (tid < 32) {
        const float e = e_lds[tid];
        e_tab[(size_t)b * DD + sx * 32 + tid] = e;
        float s = e, q = e * e;
        #pragma unroll
        for (int off = 16; off > 0; off >>= 1) {
            s += __shfl_xor(s, off);
            q += __shfl_xor(q, off);
        }
        if (tid == 0) {
            stats[((size_t)b * 16 + sx) * 2]     = s;
            stats[((size_t)b * 16 + sx) * 2 + 1] = q;
        }
    }
}

// ---------------------------------------------------------------------------
// Main: one wave per token. Lane owns dims [4l,4l+4) and [256+4l,256+4l+4).
// Token load + all branches wave-uniform; two coalesced 1KB nt-store segments.
// Grid exact: n_tokens/4 blocks of 256 (4 waves).
// ---------------------------------------------------------------------------
__global__ __launch_bounds__(256) void direct_kernel(
    const int* __restrict__ tokens,
    const float* __restrict__ token_emb,
    const float* __restrict__ time_lin_w, const float* __restrict__ time_lin_b,
    const float* __restrict__ time_w,     const float* __restrict__ time_b,
    const float* __restrict__ dur_lin_w,  const float* __restrict__ dur_lin_b,
    const float* __restrict__ dur_w,      const float* __restrict__ dur_b,
    const float* __restrict__ vel_ln_g,   const float* __restrict__ vel_ln_b,
    const float* __restrict__ e_tab,      const float* __restrict__ stats,
    float* __restrict__ out)
{
    const int wave = threadIdx.x >> 6;
    const int lane = threadIdx.x & 63;
    const int tok  = blockIdx.x * 4 + wave;
    const int t    = tokens[tok];            // wave-uniform
    float* __restrict__ orow = out + (size_t)tok * DD;
    const int d0 = lane * 4;                 // [0,256)
    const int d1 = 256 + d0;                 // [256,512)

    f32x4 r0, r1;

    if (t < CAT_VOCAB) {
        r0 = *(const f32x4*)(token_emb + (size_t)t * DD + d0);
        r1 = *(const f32x4*)(token_emb + (size_t)t * DD + d1);
    } else if (t < NOTE_START || t >= DUR_START) {
        // time2vec: r0 = linear half (weights d0), r1 = periodic half (weights d0)
        const bool is_time = (t < NOTE_START);
        const int start = is_time ? TIME_START : DUR_START;
        const float tn = (float)(t - start) / 1000.0f;
        const float* lw = is_time ? time_lin_w : dur_lin_w;
        const float* lb = is_time ? time_lin_b : dur_lin_b;
        const float* pw = is_time ? time_w    : dur_w;
        const float* pb = is_time ? time_b    : dur_b;
        const float4 w  = *(const float4*)(lw + d0);
        const float4 bb = *(const float4*)(lb + d0);
        const float4 w2 = *(const float4*)(pw + d0);
        const float4 b2 = *(const float4*)(pb + d0);
        r0.x = tn * w.x + bb.x;  r0.y = tn * w.y + bb.y;
        r0.z = tn * w.z + bb.z;  r0.w = tn * w.w + bb.w;
        r1.x = fsin(tn * w2.x + b2.x); r1.y = fsin(tn * w2.y + b2.y);
        r1.z = fsin(tn * w2.z + b2.z); r1.w = fsin(tn * w2.w + b2.w);
    } else if (t < VEL_START) {
        // pitch: lane covers group i0=lane (dims d0) and i1=64+lane (dims d1)
        const int p = t - NOTE_START;
        const float oct = (float)(p / 12);
        const float sem = (float)(p % 12);
        const float cc = 0.52359877559829887308f;   // pi/6
        {
            const float i = (float)lane;
            const float po = oct * __builtin_amdgcn_exp2f(-i);
            const float ps = sem * cc * (i + 1.0f);
            r0.x = fsin(po); r0.y = fcos(po); r0.z = fsin(ps); r0.w = fcos(ps);
        }
        {
            const float i = (float)(64 + lane);
            const float po = oct * __builtin_amdgcn_exp2f(-i);
            const float ps = sem * cc * (i + 1.0f);
            r1.x = fsin(po); r1.y = fcos(po); r1.z = fsin(ps); r1.w = fcos(ps);
        }
    } else {
        // velocity: raw e + inline LayerNorm from partial stats (wave-uniform)
        const int bin = t - VEL_START;
        float s = 0.0f, q = 0.0f;
        #pragma unroll
        for (int o = 0; o < 16; ++o) {
            s += stats[((size_t)bin * 16 + o) * 2];
            q += stats[((size_t)bin * 16 + o) * 2 + 1];
        }
        const float mu  = s * (1.0f / 512.0f);
        const float var = q * (1.0f / 512.0f) - mu * mu;
        const float inv = 1.0f / sqrtf(var + 1e-5f);
        const f32x4 e0 = *(const f32x4*)(e_tab + (size_t)bin * DD + d0);
        const f32x4 e1 = *(const f32x4*)(e_tab + (size_t)bin * DD + d1);
        const float4 g0 = *(const float4*)(vel_ln_g + d0);
        const float4 g1 = *(const float4*)(vel_ln_g + d1);
        const float4 b0 = *(const float4*)(vel_ln_b + d0);
        const float4 b1 = *(const float4*)(vel_ln_b + d1);
        r0.x = g0.x * (e0.x - mu) * inv + b0.x;
        r0.y = g0.y * (e0.y - mu) * inv + b0.y;
        r0.z = g0.z * (e0.z - mu) * inv + b0.z;
        r0.w = g0.w * (e0.w - mu) * inv + b0.w;
        r1.x = g1.x * (e1.x - mu) * inv + b1.x;
        r1.y = g1.y * (e1.y - mu) * inv + b1.y;
        r1.z = g1.z * (e1.z - mu) * inv + b1.z;
        r1.w = g1.w * (e1.w - mu) * inv + b1.w;
    }

    __builtin_nontemporal_store(r0, (f32x4*)(orow + d0));
    __builtin_nontemporal_store(r1, (f32x4*)(orow + d1));
}

// ---------------------------------------------------------------------------
// Fallback (ws too small): direct per-token kernel with inline vel matvec.
// ---------------------------------------------------------------------------
__global__ __launch_bounds__(256) void music_emb_fallback(
    const int* __restrict__ tokens,
    const float* __restrict__ token_emb,
    const float* __restrict__ time_lin_w, const float* __restrict__ time_lin_b,
    const float* __restrict__ time_w,     const float* __restrict__ time_b,
    const float* __restrict__ vel_w1,     const float* __restrict__ vel_b1,
    const float* __restrict__ vel_w2,     const float* __restrict__ vel_b2,
    const float* __restrict__ vel_ln_g,   const float* __restrict__ vel_ln_b,
    const float* __restrict__ dur_lin_w,  const float* __restrict__ dur_lin_b,
    const float* __restrict__ dur_w,      const float* __restrict__ dur_b,
    float* __restrict__ out, int n_tokens)
{
    const int wave = threadIdx.x >> 6;
    const int lane = threadIdx.x & 63;
    const int tok_idx = blockIdx.x * 4 + wave;
    if (tok_idx >= n_tokens) return;

    const int t = tokens[tok_idx];
    float* __restrict__ orow = out + (size_t)tok_idx * DD;
    const int d0 = lane * 4;
    const int d1 = 256 + lane * 4;
    float4 r0, r1;

    if (t < CAT_VOCAB) {
        r0 = *(const float4*)(token_emb + (size_t)t * DD + d0);
        r1 = *(const float4*)(token_emb + (size_t)t * DD + d1);
    } else if (t < NOTE_START || (t >= DUR_START && t < DUR_START + DUR_STEPS)) {
        const bool is_time = (t < NOTE_START);
        const float* lw = is_time ? time_lin_w : dur_lin_w;
        const float* lb = is_time ? time_lin_b : dur_lin_b;
        const float* pw = is_time ? time_w    : dur_w;
        const float* pb = is_time ? time_b    : dur_b;
        const int start = is_time ? TIME_START : DUR_START;
        const float tn = (float)(t - start) / 1000.0f;
        float a[4], p[4];
        #pragma unroll
        for (int k = 0; k < 4; ++k) {
            a[k] = tn * lw[d0 + k] + lb[d0 + k];
            p[k] = fsin(tn * pw[d0 + k] + pb[d0 + k]);
        }
        r0 = make_float4(a[0], a[1], a[2], a[3]);
        r1 = make_float4(p[0], p[1], p[2], p[3]);
    } else if (t < NOTE_START + NOTE_RANGE) {
        const int p = t - NOTE_START;
        const float oct = (float)(p / 12);
        const float sem = (float)(p % 12);
        const float cc = 0.52359877559829887308f;
        {
            const float i = (float)lane;
            const float po = oct * __builtin_amdgcn_exp2f(-i);
            const float ps = (sem * cc) * (i + 1.0f);
            r0 = make_float4(fsin(po), fcos(po), fsin(ps), fcos(ps));
        }
        {
            const float i = (float)(64 + lane);
            const float po = oct * __builtin_amdgcn_exp2f(-i);
            const float ps = (sem * cc) * (i + 1.0f);
            r1 = make_float4(fsin(po), fcos(po), fsin(ps), fcos(ps));
        }
    } else if (t < VEL_START + VEL_BINS) {
        const float vn = (float)(t - VEL_START) / 32.0f;
        float hj[4];
        #pragma unroll
        for (int k = 0; k < 4; ++k) {
            const float x = vn * vel_w1[d0 + k] + vel_b1[d0 + k];
            hj[k] = gelu_exact(x);
        }
        float e0[4], e1[4];
        #pragma unroll
        for (int k = 0; k < 4; ++k) { e0[k] = vel_b2[d0 + k]; e1[k] = vel_b2[d1 + k]; }
        for (int src = 0; src < 64; ++src) {
            const float h0 = __shfl(hj[0], src);
            const float h1 = __shfl(hj[1], src);
            const float h2 = __shfl(hj[2], src);
            const float h3 = __shfl(hj[3], src);
            const int j = src << 2;
            #pragma unroll
            for (int k = 0; k < 4; ++k) {
                const float4 wa = *(const float4*)(vel_w2 + (size_t)(d0 + k) * 256 + j);
                const float4 wb = *(const float4*)(vel_w2 + (size_t)(d1 + k) * 256 + j);
                e0[k] += h0 * wa.x + h1 * wa.y + h2 * wa.z + h3 * wa.w;
                e1[k] += h0 * wb.x + h1 * wb.y + h2 * wb.z + h3 * wb.w;
            }
        }
        float s1 = 0.0f;
        #pragma unroll
        for (int k = 0; k < 4; ++k) s1 += e0[k] + e1[k];
        #pragma unroll
        for (int off = 32; off > 0; off >>= 1) s1 += __shfl_xor(s1, off);
        const float mu = s1 * (1.0f / 512.0f);
        float s2 = 0.0f;
        #pragma unroll
        for (int k = 0; k < 4; ++k) {
            const float a = e0[k] - mu, bb = e1[k] - mu;
            s2 += a * a + bb * bb;
        }
        #pragma unroll
        for (int off = 32; off > 0; off >>= 1) s2 += __shfl_xor(s2, off);
        const float inv = 1.0f / sqrtf(s2 * (1.0f / 512.0f) + 1e-5f);
        #pragma unroll
        for (int k = 0; k < 4; ++k) {
            e0[k] = vel_ln_g[d0 + k] * (e0[k] - mu) * inv + vel_ln_b[d0 + k];
            e1[k] = vel_ln_g[d1 + k] * (e1[k] - mu) * inv + vel_ln_b[d1 + k];
        }
        r0 = make_float4(e0[0], e0[1], e0[2], e0[3]);
        r1 = make_float4(e1[0], e1[1], e1[2], e1[3]);
    } else {
        r0 = make_float4(0.f, 0.f, 0.f, 0.f);
        r1 = make_float4(0.f, 0.f, 0.f, 0.f);
    }

    *(float4*)(orow + d0) = r0;
    *(float4*)(orow + d1) = r1;
}

extern "C" void kernel_launch(void* const* d_in, const int* in_sizes, int n_in,
                              void* d_out, int out_size, void* d_ws, size_t ws_size,
                              hipStream_t stream) {
    const int*   tokens     = (const int*)  d_in[0];
    const float* token_emb  = (const float*)d_in[1];
    const float* time_lin_w = (const float*)d_in[2];
    const float* time_lin_b = (const float*)d_in[3];
    const float* time_w     = (const float*)d_in[4];
    const float* time_b     = (const float*)d_in[5];
    const float* vel_w1     = (const float*)d_in[6];
    const float* vel_b1     = (const float*)d_in[7];
    const float* vel_w2     = (const float*)d_in[8];
    const float* vel_b2     = (const float*)d_in[9];
    const float* vel_ln_g   = (const float*)d_in[10];
    const float* vel_ln_b   = (const float*)d_in[11];
    const float* dur_lin_w  = (const float*)d_in[12];
    const float* dur_lin_b  = (const float*)d_in[13];
    const float* dur_w      = (const float*)d_in[14];
    const float* dur_b      = (const float*)d_in[15];
    float* out = (float*)d_out;

    const int n_tokens = in_sizes[0];                                     // 65536
    const size_t e_bytes     = (size_t)VEL_BINS * DD * sizeof(float);     // 64 KB
    const size_t stats_bytes = (size_t)VEL_BINS * 16 * 2 * sizeof(float); // 4 KB

    if (ws_size >= e_bytes + stats_bytes && (n_tokens & 3) == 0) {
        float* e_tab = (float*)d_ws;
        float* stats = (float*)((char*)d_ws + e_bytes);

        hipLaunchKernelGGL(vel_e_kernel, dim3(VEL_BINS * 16), dim3(256), 0, stream,
                           vel_w1, vel_b1, vel_w2, vel_b2, e_tab, stats);

        hipLaunchKernelGGL(direct_kernel, dim3(n_tokens / 4), dim3(256), 0, stream,
                           tokens, token_emb,
                           time_lin_w, time_lin_b, time_w, time_b,
                           dur_lin_w, dur_lin_b, dur_w, dur_b,
                           vel_ln_g, vel_ln_b, e_tab, stats,
                           out);
    } else {
        const int blocks = (n_tokens + 3) / 4;
        hipLaunchKernelGGL(music_emb_fallback, dim3(blocks), dim3(256), 0, stream,
                           tokens, token_emb,
                           time_lin_w, time_lin_b, time_w, time_b,
                           vel_w1, vel_b1, vel_w2, vel_b2, vel_ln_g, vel_ln_b,
                           dur_lin_w, dur_lin_b, dur_w, dur_b,
                           out, n_tokens);
    }
}

// Round 9
// 30.725 us; speedup vs baseline: 1.0672x; 1.0672x over previous
//
#include <hip/hip_runtime.h>
#include <math.h>

#define DD 512
#define CAT_VOCAB 512
#define TIME_START 512
#define TIME_STEPS 1000
#define NOTE_START 1512
#define NOTE_RANGE 128
#define VEL_START 1640
#define VEL_BINS 32
#define DUR_START 1672
#define DUR_STEPS 1000
#define VOCAB 2672

typedef float f32x4 __attribute__((ext_vector_type(4)));

__device__ __forceinline__ float gelu_exact(float x) {
    return 0.5f * x * (1.0f + erff(x * 0.70710678118654752440f));
}

// hardware trig: reduce to revolutions in [0,1), then v_sin/v_cos.
// |x| <= ~740 rad here -> reduction error <= ~6e-5, far under 8.25e-2 threshold.
__device__ __forceinline__ float fsin(float x) {
    float r = x * 0.15915494309189535f;   // x / (2*pi)
    r = r - floorf(r);
    return __builtin_amdgcn_sinf(r);
}
__device__ __forceinline__ float fcos(float x) {
    float r = x * 0.15915494309189535f;
    r = r - floorf(r);
    return __builtin_amdgcn_cosf(r);
}

// ---------------------------------------------------------------------------
// Kernel A (R8 version): velocity e-matvec, 512 blocks = (bin, sixteenth).
// 8 rows per wave, single flight group (max ILP, no serial loop).
// Writes raw e[32][512] and per-sixteenth partial stats (sum, sumsq).
// ---------------------------------------------------------------------------
__global__ __launch_bounds__(256) void vel_e_kernel(
    const float* __restrict__ vel_w1, const float* __restrict__ vel_b1,
    const float* __restrict__ vel_w2, const float* __restrict__ vel_b2,
    float* __restrict__ e_tab,        // [32][512]
    float* __restrict__ stats)        // [32][16][2]
{
    __shared__ float e_lds[32];

    const int blk = blockIdx.x;           // 0..511
    const int b   = blk >> 4;             // bin 0..31
    const int sx  = blk & 15;             // sixteenth 0..15
    const float vn = (float)b / 32.0f;
    const int tid = threadIdx.x;
    const int lane = tid & 63;
    const int wave = tid >> 6;

    const float4 w1v = *(const float4*)(vel_w1 + lane * 4);
    const float4 b1v = *(const float4*)(vel_b1 + lane * 4);
    float4 hv;
    hv.x = gelu_exact(vn * w1v.x + b1v.x);
    hv.y = gelu_exact(vn * w1v.y + b1v.y);
    hv.z = gelu_exact(vn * w1v.z + b1v.z);
    hv.w = gelu_exact(vn * w1v.w + b1v.w);

    const int rbase = sx * 32 + wave * 8;  // row within bin
    float p[8];
    #pragma unroll
    for (int k = 0; k < 8; ++k) {
        const float4 w2v = *(const float4*)(vel_w2 + (size_t)(rbase + k) * 256 + lane * 4);
        p[k] = w2v.x * hv.x + w2v.y * hv.y + w2v.z * hv.z + w2v.w * hv.w;
    }
    #pragma unroll
    for (int off = 32; off > 0; off >>= 1) {
        #pragma unroll
        for (int k = 0; k < 8; ++k) p[k] += __shfl_xor(p[k], off);
    }
    #pragma unroll
    for (int k = 0; k < 8; ++k) {
        if (lane == k) e_lds[wave * 8 + k] = p[k] + vel_b2[rbase + k];
    }
    __syncthreads();

    if (tid < 32) {
        const float e = e_lds[tid];
        e_tab[(size_t)b * DD + sx * 32 + tid] = e;
        float s = e, q = e * e;
        #pragma unroll
        for (int off = 16; off > 0; off >>= 1) {
            s += __shfl_xor(s, off);
            q += __shfl_xor(q, off);
        }
        if (tid == 0) {
            stats[((size_t)b * 16 + sx) * 2]     = s;
            stats[((size_t)b * 16 + sx) * 2 + 1] = q;
        }
    }
}

// ---------------------------------------------------------------------------
// Main (R7 version): one float4 chunk per thread, no loop. Token wave-uniform
// (changes every 128 threads). Velocity LN inline from e_tab + partial stats.
// Nontemporal stores. 32768 blocks for max TLP.
// ---------------------------------------------------------------------------
__global__ __launch_bounds__(256) void direct_kernel(
    const int* __restrict__ tokens,
    const float* __restrict__ token_emb,
    const float* __restrict__ time_lin_w, const float* __restrict__ time_lin_b,
    const float* __restrict__ time_w,     const float* __restrict__ time_b,
    const float* __restrict__ dur_lin_w,  const float* __restrict__ dur_lin_b,
    const float* __restrict__ dur_w,      const float* __restrict__ dur_b,
    const float* __restrict__ vel_ln_g,   const float* __restrict__ vel_ln_b,
    const float* __restrict__ e_tab,      const float* __restrict__ stats,
    float* __restrict__ out, int total_chunks)
{
    const int c = blockIdx.x * 256 + threadIdx.x;
    if (c >= total_chunks) return;

    const int tok = c >> 7;        // token index
    const int ch  = c & 127;       // chunk within row
    const int d   = ch * 4;        // first dim of chunk
    const int t   = tokens[tok];   // wave-uniform (broadcast load)

    f32x4 v;

    if (t < CAT_VOCAB) {
        v = *(const f32x4*)(token_emb + (size_t)t * DD + d);
    } else if (t < NOTE_START || t >= DUR_START) {
        const bool is_time = (t < NOTE_START);
        const int start = is_time ? TIME_START : DUR_START;
        const float tn = (float)(t - start) / 1000.0f;
        if (ch < 64) {   // linear half, dims [0,256)
            const float* lw = is_time ? time_lin_w : dur_lin_w;
            const float* lb = is_time ? time_lin_b : dur_lin_b;
            const float4 w = *(const float4*)(lw + d);
            const float4 b = *(const float4*)(lb + d);
            v.x = tn * w.x + b.x; v.y = tn * w.y + b.y;
            v.z = tn * w.z + b.z; v.w = tn * w.w + b.w;
        } else {         // periodic half, dims [256,512)
            const float* pw = is_time ? time_w : dur_w;
            const float* pb = is_time ? time_b : dur_b;
            const float4 w = *(const float4*)(pw + d - 256);
            const float4 b = *(const float4*)(pb + d - 256);
            v.x = fsin(tn * w.x + b.x); v.y = fsin(tn * w.y + b.y);
            v.z = fsin(tn * w.z + b.z); v.w = fsin(tn * w.w + b.w);
        }
    } else if (t < VEL_START) {
        // pitch: group i = ch, dims (sin po, cos po, sin ps, cos ps)
        const int p = t - NOTE_START;
        const float oct = (float)(p / 12);
        const float sem = (float)(p % 12);
        const float po = oct * __builtin_amdgcn_exp2f(-(float)ch);
        const float ps = sem * 0.52359877559829887308f * ((float)ch + 1.0f);
        v.x = fsin(po); v.y = fcos(po); v.z = fsin(ps); v.w = fcos(ps);
    } else {
        // velocity: raw e from ws + inline LayerNorm from partial stats
        const int bin = t - VEL_START;
        const f32x4 e = *(const f32x4*)(e_tab + (size_t)bin * DD + d);
        float s = 0.0f, q = 0.0f;
        #pragma unroll
        for (int o = 0; o < 16; ++o) {
            s += stats[((size_t)bin * 16 + o) * 2];
            q += stats[((size_t)bin * 16 + o) * 2 + 1];
        }
        const float mu  = s * (1.0f / 512.0f);
        const float var = q * (1.0f / 512.0f) - mu * mu;
        const float inv = 1.0f / sqrtf(var + 1e-5f);
        const float4 g  = *(const float4*)(vel_ln_g + d);
        const float4 be = *(const float4*)(vel_ln_b + d);
        v.x = g.x * (e.x - mu) * inv + be.x;
        v.y = g.y * (e.y - mu) * inv + be.y;
        v.z = g.z * (e.z - mu) * inv + be.z;
        v.w = g.w * (e.w - mu) * inv + be.w;
    }

    __builtin_nontemporal_store(v, (f32x4*)(out + (size_t)c * 4));
}

// ---------------------------------------------------------------------------
// Fallback (ws too small): direct per-token kernel with inline vel matvec.
// ---------------------------------------------------------------------------
__global__ __launch_bounds__(256) void music_emb_fallback(
    const int* __restrict__ tokens,
    const float* __restrict__ token_emb,
    const float* __restrict__ time_lin_w, const float* __restrict__ time_lin_b,
    const float* __restrict__ time_w,     const float* __restrict__ time_b,
    const float* __restrict__ vel_w1,     const float* __restrict__ vel_b1,
    const float* __restrict__ vel_w2,     const float* __restrict__ vel_b2,
    const float* __restrict__ vel_ln_g,   const float* __restrict__ vel_ln_b,
    const float* __restrict__ dur_lin_w,  const float* __restrict__ dur_lin_b,
    const float* __restrict__ dur_w,      const float* __restrict__ dur_b,
    float* __restrict__ out, int n_tokens)
{
    const int wave = threadIdx.x >> 6;
    const int lane = threadIdx.x & 63;
    const int tok_idx = blockIdx.x * 4 + wave;
    if (tok_idx >= n_tokens) return;

    const int t = tokens[tok_idx];
    float* __restrict__ orow = out + (size_t)tok_idx * DD;
    const int d0 = lane * 4;
    const int d1 = 256 + lane * 4;
    float4 r0, r1;

    if (t < CAT_VOCAB) {
        r0 = *(const float4*)(token_emb + (size_t)t * DD + d0);
        r1 = *(const float4*)(token_emb + (size_t)t * DD + d1);
    } else if (t < NOTE_START || (t >= DUR_START && t < DUR_START + DUR_STEPS)) {
        const bool is_time = (t < NOTE_START);
        const float* lw = is_time ? time_lin_w : dur_lin_w;
        const float* lb = is_time ? time_lin_b : dur_lin_b;
        const float* pw = is_time ? time_w    : dur_w;
        const float* pb = is_time ? time_b    : dur_b;
        const int start = is_time ? TIME_START : DUR_START;
        const float tn = (float)(t - start) / 1000.0f;
        float a[4], p[4];
        #pragma unroll
        for (int k = 0; k < 4; ++k) {
            a[k] = tn * lw[d0 + k] + lb[d0 + k];
            p[k] = fsin(tn * pw[d0 + k] + pb[d0 + k]);
        }
        r0 = make_float4(a[0], a[1], a[2], a[3]);
        r1 = make_float4(p[0], p[1], p[2], p[3]);
    } else if (t < NOTE_START + NOTE_RANGE) {
        const int p = t - NOTE_START;
        const float oct = (float)(p / 12);
        const float sem = (float)(p % 12);
        const float cc = 0.52359877559829887308f;
        {
            const float i = (float)lane;
            const float po = oct * __builtin_amdgcn_exp2f(-i);
            const float ps = (sem * cc) * (i + 1.0f);
            r0 = make_float4(fsin(po), fcos(po), fsin(ps), fcos(ps));
        }
        {
            const float i = (float)(64 + lane);
            const float po = oct * __builtin_amdgcn_exp2f(-i);
            const float ps = (sem * cc) * (i + 1.0f);
            r1 = make_float4(fsin(po), fcos(po), fsin(ps), fcos(ps));
        }
    } else if (t < VEL_START + VEL_BINS) {
        const float vn = (float)(t - VEL_START) / 32.0f;
        float hj[4];
        #pragma unroll
        for (int k = 0; k < 4; ++k) {
            const float x = vn * vel_w1[d0 + k] + vel_b1[d0 + k];
            hj[k] = gelu_exact(x);
        }
        float e0[4], e1[4];
        #pragma unroll
        for (int k = 0; k < 4; ++k) { e0[k] = vel_b2[d0 + k]; e1[k] = vel_b2[d1 + k]; }
        for (int src = 0; src < 64; ++src) {
            const float h0 = __shfl(hj[0], src);
            const float h1 = __shfl(hj[1], src);
            const float h2 = __shfl(hj[2], src);
            const float h3 = __shfl(hj[3], src);
            const int j = src << 2;
            #pragma unroll
            for (int k = 0; k < 4; ++k) {
                const float4 wa = *(const float4*)(vel_w2 + (size_t)(d0 + k) * 256 + j);
                const float4 wb = *(const float4*)(vel_w2 + (size_t)(d1 + k) * 256 + j);
                e0[k] += h0 * wa.x + h1 * wa.y + h2 * wa.z + h3 * wa.w;
                e1[k] += h0 * wb.x + h1 * wb.y + h2 * wb.z + h3 * wb.w;
            }
        }
        float s1 = 0.0f;
        #pragma unroll
        for (int k = 0; k < 4; ++k) s1 += e0[k] + e1[k];
        #pragma unroll
        for (int off = 32; off > 0; off >>= 1) s1 += __shfl_xor(s1, off);
        const float mu = s1 * (1.0f / 512.0f);
        float s2 = 0.0f;
        #pragma unroll
        for (int k = 0; k < 4; ++k) {
            const float a = e0[k] - mu, bb = e1[k] - mu;
            s2 += a * a + bb * bb;
        }
        #pragma unroll
        for (int off = 32; off > 0; off >>= 1) s2 += __shfl_xor(s2, off);
        const float inv = 1.0f / sqrtf(s2 * (1.0f / 512.0f) + 1e-5f);
        #pragma unroll
        for (int k = 0; k < 4; ++k) {
            e0[k] = vel_ln_g[d0 + k] * (e0[k] - mu) * inv + vel_ln_b[d0 + k];
            e1[k] = vel_ln_g[d1 + k] * (e1[k] - mu) * inv + vel_ln_b[d1 + k];
        }
        r0 = make_float4(e0[0], e0[1], e0[2], e0[3]);
        r1 = make_float4(e1[0], e1[1], e1[2], e1[3]);
    } else {
        r0 = make_float4(0.f, 0.f, 0.f, 0.f);
        r1 = make_float4(0.f, 0.f, 0.f, 0.f);
    }

    *(float4*)(orow + d0) = r0;
    *(float4*)(orow + d1) = r1;
}

extern "C" void kernel_launch(void* const* d_in, const int* in_sizes, int n_in,
                              void* d_out, int out_size, void* d_ws, size_t ws_size,
                              hipStream_t stream) {
    const int*   tokens     = (const int*)  d_in[0];
    const float* token_emb  = (const float*)d_in[1];
    const float* time_lin_w = (const float*)d_in[2];
    const float* time_lin_b = (const float*)d_in[3];
    const float* time_w     = (const float*)d_in[4];
    const float* time_b     = (const float*)d_in[5];
    const float* vel_w1     = (const float*)d_in[6];
    const float* vel_b1     = (const float*)d_in[7];
    const float* vel_w2     = (const float*)d_in[8];
    const float* vel_b2     = (const float*)d_in[9];
    const float* vel_ln_g   = (const float*)d_in[10];
    const float* vel_ln_b   = (const float*)d_in[11];
    const float* dur_lin_w  = (const float*)d_in[12];
    const float* dur_lin_b  = (const float*)d_in[13];
    const float* dur_w      = (const float*)d_in[14];
    const float* dur_b      = (const float*)d_in[15];
    float* out = (float*)d_out;

    const int n_tokens = in_sizes[0];                                     // 65536
    const size_t e_bytes     = (size_t)VEL_BINS * DD * sizeof(float);     // 64 KB
    const size_t stats_bytes = (size_t)VEL_BINS * 16 * 2 * sizeof(float); // 4 KB

    if (ws_size >= e_bytes + stats_bytes) {
        float* e_tab = (float*)d_ws;
        float* stats = (float*)((char*)d_ws + e_bytes);

        hipLaunchKernelGGL(vel_e_kernel, dim3(VEL_BINS * 16), dim3(256), 0, stream,
                           vel_w1, vel_b1, vel_w2, vel_b2, e_tab, stats);

        const int total_chunks = n_tokens * (DD / 4);                     // 8,388,608
        const int blocks = (total_chunks + 255) / 256;                    // 32768
        hipLaunchKernelGGL(direct_kernel, dim3(blocks), dim3(256), 0, stream,
                           tokens, token_emb,
                           time_lin_w, time_lin_b, time_w, time_b,
                           dur_lin_w, dur_lin_b, dur_w, dur_b,
                           vel_ln_g, vel_ln_b, e_tab, stats,
                           out, total_chunks);
    } else {
        const int blocks = (n_tokens + 3) / 4;
        hipLaunchKernelGGL(music_emb_fallback, dim3(blocks), dim3(256), 0, stream,
                           tokens, token_emb,
                           time_lin_w, time_lin_b, time_w, time_b,
                           vel_w1, vel_b1, vel_w2, vel_b2, vel_ln_g, vel_ln_b,
                           dur_lin_w, dur_lin_b, dur_w, dur_b,
                           out, n_tokens);
    }
}